// Round 1
// baseline (5360.077 us; speedup 1.0000x reference)
//
#include <hip/hip_runtime.h>

// StageBlocks: FPS -> ball-query -> conv/BN/max -> 2x InvResMLP on MI355X.
// All discrete decisions (FPS argmax, ball membership) use contract-off f32
// to match XLA's sub/mul/add rounding bitwise. BN handled via sufficient
// statistics (sum/sumsq per channel, or 3-dim moments for the 3->128 convs).

#define BB 4
#define NN 8192
#define MM 2048
#define KK 32
#define CI 64
#define CO 128

__device__ __forceinline__ float sq3(float dx, float dy, float dz) {
#pragma clang fp contract(off)
  return dx * dx + dy * dy + dz * dz;  // ((x+y)+z), no FMA: matches XLA/np
}

// ---------------- zero stats ----------------
__global__ void k_zero(double* s) {
  int i = blockIdx.x * 256 + threadIdx.x;
  if (i < 2048) s[i] = 0.0;
}

// ---------------- FPS: one block per batch ----------------
__global__ __launch_bounds__(1024) void k_fps(const float* __restrict__ pos,
                                              float* __restrict__ cent) {
  int b = blockIdx.x;
  const float* P = pos + (size_t)b * NN * 3;
  float* C = cent + (size_t)b * MM * 3;
  int t = threadIdx.x;
  int lane = t & 63, w = t >> 6;
  float px[8], py[8], pz[8], dis[8];
#pragma unroll
  for (int s = 0; s < 8; s++) {
    int idx = (s << 10) + t;
    px[s] = P[idx * 3 + 0];
    py[s] = P[idx * 3 + 1];
    pz[s] = P[idx * 3 + 2];
    dis[s] = 1e10f;
  }
  __shared__ float s_l[3];
  __shared__ float s_cv[16], s_cx[16], s_cy[16], s_cz[16];
  __shared__ int s_ci[16];
  if (t == 0) {
    s_l[0] = P[0]; s_l[1] = P[1]; s_l[2] = P[2];
    C[0] = P[0]; C[1] = P[1]; C[2] = P[2];
  }
  __syncthreads();
  for (int m = 1; m < MM; m++) {
    float lx = s_l[0], ly = s_l[1], lz = s_l[2];
    float bv = -1.0f, bx = 0.f, by = 0.f, bz = 0.f;
    int bi = 0;
#pragma unroll
    for (int s = 0; s < 8; s++) {
      float d2 = sq3(px[s] - lx, py[s] - ly, pz[s] - lz);
      float nd = dis[s] < d2 ? dis[s] : d2;
      dis[s] = nd;
      if (nd > bv) {  // slots ascend in index -> first-max kept
        bv = nd; bi = (s << 10) + t; bx = px[s]; by = py[s]; bz = pz[s];
      }
    }
#pragma unroll
    for (int off = 32; off > 0; off >>= 1) {
      float ov = __shfl_xor(bv, off);
      int oi = __shfl_xor(bi, off);
      float ox = __shfl_xor(bx, off);
      float oy = __shfl_xor(by, off);
      float oz = __shfl_xor(bz, off);
      if (ov > bv || (ov == bv && oi < bi)) {
        bv = ov; bi = oi; bx = ox; by = oy; bz = oz;
      }
    }
    if (lane == 0) {
      s_cv[w] = bv; s_ci[w] = bi; s_cx[w] = bx; s_cy[w] = by; s_cz[w] = bz;
    }
    __syncthreads();
    if (w == 0 && lane < 16) {
      float cv = s_cv[lane], cx = s_cx[lane], cy = s_cy[lane], cz = s_cz[lane];
      int ci = s_ci[lane];
#pragma unroll
      for (int off = 8; off > 0; off >>= 1) {
        float ov = __shfl_xor(cv, off);
        int oi = __shfl_xor(ci, off);
        float ox = __shfl_xor(cx, off);
        float oy = __shfl_xor(cy, off);
        float oz = __shfl_xor(cz, off);
        if (ov > cv || (ov == cv && oi < ci)) {
          cv = ov; ci = oi; cx = ox; cy = oy; cz = oz;
        }
      }
      if (lane == 0) {
        s_l[0] = cx; s_l[1] = cy; s_l[2] = cz;
        C[m * 3 + 0] = cx; C[m * 3 + 1] = cy; C[m * 3 + 2] = cz;
      }
    }
    __syncthreads();
  }
}

// ---------------- ball query: one wave per (b,m) pair ----------------
// Writes first-K in-ball indices (index order, padded with first hit) and
// accumulates 9 moments of the normalized offsets (for analytic BN).
__global__ __launch_bounds__(256) void k_bq(const float* __restrict__ pts,
                                            const float* __restrict__ cent,
                                            int npts, float rsq, float inv_r,
                                            int* __restrict__ sel,
                                            double* __restrict__ mom) {
  int lane = threadIdx.x & 63, w = threadIdx.x >> 6;
  int pair = blockIdx.x * 4 + w;
  int b = pair / MM;
  const float* P = pts + (size_t)b * npts * 3;
  const float* C = cent + (size_t)pair * 3;
  float cx = C[0], cy = C[1], cz = C[2];
  __shared__ int s_sel[4][KK];
  __shared__ float s_mom[4][9];
  int cnt = 0;
  int nch = npts >> 6;
  for (int ch = 0; ch < nch; ch++) {
    int i = (ch << 6) + lane;
    float d2 = sq3(P[i * 3 + 0] - cx, P[i * 3 + 1] - cy, P[i * 3 + 2] - cz);
    bool hit = d2 < rsq;
    unsigned long long mk = __ballot(hit);
    if (mk) {
      int pre = __popcll(mk & ((1ull << lane) - 1ull));
      int k = cnt + pre;
      if (hit && k < KK) s_sel[w][k] = i;
      cnt += __popcll(mk);
      if (cnt >= KK) break;
    }
  }
  int total = cnt < KK ? cnt : KK;  // >=1 (query point is in the set, d2==0)
  int myidx = 0;
  if (lane < KK) {
    int v = (lane < total) ? s_sel[w][lane] : s_sel[w][0];
    s_sel[w][lane] = v;
    sel[(size_t)pair * KK + lane] = v;
    myidx = v;
  }
  float gx = 0.f, gy = 0.f, gz = 0.f;
  if (lane < KK) {
    gx = (P[myidx * 3 + 0] - cx) * inv_r;
    gy = (P[myidx * 3 + 1] - cy) * inv_r;
    gz = (P[myidx * 3 + 2] - cz) * inv_r;
  }
  float v9[9] = {gx, gy, gz, gx * gx, gx * gy, gx * gz, gy * gy, gy * gz, gz * gz};
#pragma unroll
  for (int j = 0; j < 9; j++) {
#pragma unroll
    for (int off = 32; off > 0; off >>= 1) v9[j] += __shfl_xor(v9[j], off);
  }
  if (lane == 0) {
#pragma unroll
    for (int j = 0; j < 9; j++) s_mom[w][j] = v9[j];
  }
  __syncthreads();
  if (threadIdx.x < 9) {
    double a = (double)s_mom[0][threadIdx.x] + s_mom[1][threadIdx.x] +
               s_mom[2][threadIdx.x] + s_mom[3][threadIdx.x];
    atomicAdd(&mom[threadIdx.x], a);
  }
}

// ---------------- pointwise conv (CIN->128) + BN stats ----------------
// thread = channel o (x2 rows); W row in VGPRs; input rows via scalar loads.
template <int CIN, bool TRANS>
__global__ __launch_bounds__(256) void k_conv(const float* __restrict__ in,
                                              const float* __restrict__ W,
                                              const float* __restrict__ isc,
                                              const float* __restrict__ ish,
                                              float* __restrict__ out,
                                              double* __restrict__ stats,
                                              int rows_per_block) {
  int o = threadIdx.x & 127, half = threadIdx.x >> 7;
  float4 w[CIN / 4];
  const float4* Wv = (const float4*)(W + (size_t)o * CIN);
#pragma unroll
  for (int i = 0; i < CIN / 4; i++) w[i] = Wv[i];
  int row0 = blockIdx.x * rows_per_block;
  float ssum = 0.f, ssq = 0.f;
  for (int r = 0; r < rows_per_block; r += 2) {
    int row = __builtin_amdgcn_readfirstlane(row0 + r + half);
    const float* xr = in + (size_t)row * CIN;
    float acc = 0.f;
#pragma unroll
    for (int i = 0; i < CIN / 4; i++) {
      float4 a = *(const float4*)(xr + 4 * i);
      if (TRANS) {
        a.x = fmaxf(a.x * isc[4 * i + 0] + ish[4 * i + 0], 0.f);
        a.y = fmaxf(a.y * isc[4 * i + 1] + ish[4 * i + 1], 0.f);
        a.z = fmaxf(a.z * isc[4 * i + 2] + ish[4 * i + 2], 0.f);
        a.w = fmaxf(a.w * isc[4 * i + 3] + ish[4 * i + 3], 0.f);
      }
      acc += a.x * w[i].x + a.y * w[i].y + a.z * w[i].z + a.w * w[i].w;
    }
    out[(size_t)row * CO + o] = acc;
    ssum += acc;
    ssq += acc * acc;
  }
  atomicAdd(&stats[o], (double)ssum);
  atomicAdd(&stats[128 + o], (double)ssq);
}

// ---------------- BN finalize: (sum,sumsq) -> scale/shift ----------------
__global__ void k_fin_stats(const double* __restrict__ st,
                            const float* __restrict__ gam,
                            const float* __restrict__ bet,
                            float* __restrict__ sc, float* __restrict__ sh,
                            double cnt) {
  int t = threadIdx.x;
  double mean = st[t] / cnt;
  double var = st[128 + t] / cnt - mean * mean;
  if (var < 0) var = 0;
  double s = (double)gam[t] / sqrt(var + 1e-5);
  sc[t] = (float)s;
  sh[t] = (float)((double)bet[t] - mean * s);
}

// BN finalize from 3-dim moments: mean_o = W mu, var_o = W S2 W^T - mean^2
__global__ void k_fin_mom(const double* __restrict__ mo,
                          const float* __restrict__ Wp,
                          const float* __restrict__ gam,
                          const float* __restrict__ bet, float* __restrict__ sc,
                          float* __restrict__ sh, double cnt) {
  int t = threadIdx.x;
  double w0 = Wp[t * 3 + 0], w1 = Wp[t * 3 + 1], w2 = Wp[t * 3 + 2];
  double mx = mo[0] / cnt, my = mo[1] / cnt, mz = mo[2] / cnt;
  double sxx = mo[3] / cnt, sxy = mo[4] / cnt, sxz = mo[5] / cnt;
  double syy = mo[6] / cnt, syz = mo[7] / cnt, szz = mo[8] / cnt;
  double mean = w0 * mx + w1 * my + w2 * mz;
  double ey2 = w0 * w0 * sxx + w1 * w1 * syy + w2 * w2 * szz +
               2.0 * (w0 * w1 * sxy + w0 * w2 * sxz + w1 * w2 * syz);
  double var = ey2 - mean * mean;
  if (var < 0) var = 0;
  double s = (double)gam[t] / sqrt(var + 1e-5);
  sc[t] = (float)s;
  sh[t] = (float)((double)bet[t] - mean * s);
}

// ---------------- stage-1 aggregation: xf = max_k(relu(bn(feat)) + relu(bn(Wps*gpn)))
__global__ __launch_bounds__(128) void k_xf(
    const float* __restrict__ pos, const float* __restrict__ cent,
    const int* __restrict__ sel1, const float* __restrict__ fpre,
    const float* __restrict__ Wps, const float* __restrict__ scp,
    const float* __restrict__ shp, const float* __restrict__ scx,
    const float* __restrict__ shx, float* __restrict__ xf) {
  int pair = blockIdx.x;
  int b = pair >> 11;
  int o = threadIdx.x;
  float w0 = Wps[o * 3 + 0], w1 = Wps[o * 3 + 1], w2 = Wps[o * 3 + 2];
  float sp = scp[o], hp = shp[o], sx = scx[o], hx = shx[o];
  const float* C = cent + (size_t)pair * 3;
  float cx = C[0], cy = C[1], cz = C[2];
  const float* P = pos + (size_t)b * NN * 3;
  const float* F = fpre + (size_t)b * NN * CO;
  __shared__ int s_idx[KK];
  if (o < KK) s_idx[o] = sel1[(size_t)pair * KK + o];
  __syncthreads();
  float acc = -1e30f;
#pragma unroll 4
  for (int k = 0; k < KK; k++) {
    int idx = __builtin_amdgcn_readfirstlane(s_idx[k]);
    float gx = (P[idx * 3 + 0] - cx) * 10.0f;
    float gy = (P[idx * 3 + 1] - cy) * 10.0f;
    float gz = (P[idx * 3 + 2] - cz) * 10.0f;
    float y = fmaxf((w0 * gx + w1 * gy + w2 * gz) * sp + hp, 0.f);
    float f = fmaxf(F[(size_t)idx * CO + o] * sx + hx, 0.f);
    float v = y + f;
    acc = v > acc ? v : acc;
  }
  xf[(size_t)pair * CO + o] = acc;
}

// ---------------- block aggregation: g = max_k(relu(bn(y1[sel2])) + pe)
__global__ __launch_bounds__(128) void k_g(
    const float* __restrict__ cent, const int* __restrict__ sel2,
    const float* __restrict__ y1, const float* __restrict__ sc1,
    const float* __restrict__ sh1, const float* __restrict__ Wpe,
    const float* __restrict__ spe, const float* __restrict__ hpe,
    float* __restrict__ g) {
  int pair = blockIdx.x;
  int b = pair >> 11;
  int o = threadIdx.x;
  float w0 = Wpe[o * 3 + 0], w1 = Wpe[o * 3 + 1], w2 = Wpe[o * 3 + 2];
  float se = spe[o], he = hpe[o], s1 = sc1[o], h1 = sh1[o];
  const float* C = cent + (size_t)pair * 3;
  float cx = C[0], cy = C[1], cz = C[2];
  const float* CB = cent + (size_t)b * MM * 3;
  const float* Y = y1 + (size_t)b * MM * CO;
  __shared__ int s_idx[KK];
  if (o < KK) s_idx[o] = sel2[(size_t)pair * KK + o];
  __syncthreads();
  float acc = -1e30f;
#pragma unroll 4
  for (int k = 0; k < KK; k++) {
    int idx = __builtin_amdgcn_readfirstlane(s_idx[k]);
    float gx = (CB[idx * 3 + 0] - cx) * 5.0f;
    float gy = (CB[idx * 3 + 1] - cy) * 5.0f;
    float gz = (CB[idx * 3 + 2] - cz) * 5.0f;
    float pe = fmaxf((w0 * gx + w1 * gy + w2 * gz) * se + he, 0.f);
    float f = fmaxf(Y[(size_t)idx * CO + o] * s1 + h1, 0.f);
    float v = pe + f;
    acc = v > acc ? v : acc;
  }
  g[(size_t)pair * CO + o] = acc;
}

// ---------------- residual: xf = relu(relu(bn(y1)) + bn(y2b)) ----------------
__global__ __launch_bounds__(256) void k_resid(
    const float* __restrict__ y1, const float* __restrict__ sc1,
    const float* __restrict__ sh1, const float* __restrict__ y2,
    const float* __restrict__ sc2, const float* __restrict__ sh2,
    float* __restrict__ xf) {
  int i = blockIdx.x * 256 + threadIdx.x;
  int o = i & 127;
  float f = fmaxf(y1[i] * sc1[o] + sh1[o], 0.f);
  float v = y2[i] * sc2[o] + sh2[o];
  xf[i] = fmaxf(f + v, 0.f);
}

extern "C" void kernel_launch(void* const* d_in, const int* in_sizes, int n_in,
                              void* d_out, int out_size, void* d_ws,
                              size_t ws_size, hipStream_t stream) {
  const float* pos = (const float*)d_in[0];
  const float* x = (const float*)d_in[1];
  const float* W_x = (const float*)d_in[2];
  const float* g_x = (const float*)d_in[3];
  const float* b_x = (const float*)d_in[4];
  const float* W_ps = (const float*)d_in[5];
  const float* g_ps = (const float*)d_in[6];
  const float* b_ps = (const float*)d_in[7];
  const float* W_pe = (const float*)d_in[8];
  const float* g_pe = (const float*)d_in[9];
  const float* b_pe = (const float*)d_in[10];
  const float* W1 = (const float*)d_in[11];
  const float* g1 = (const float*)d_in[12];
  const float* b1 = (const float*)d_in[13];
  const float* W2a = (const float*)d_in[14];
  const float* g2a = (const float*)d_in[15];
  const float* b2a = (const float*)d_in[16];
  const float* W2b = (const float*)d_in[17];
  const float* g2b = (const float*)d_in[18];
  const float* b2b = (const float*)d_in[19];

  float* cent = (float*)d_out;              // (B,M,3)
  float* xf = cent + (size_t)BB * MM * 3;   // (B,M,128)

  char* p = (char*)d_ws;
  double* stats = (double*)p; p += 2048 * sizeof(double);
  float* scsh = (float*)p;    p += 32 * 128 * sizeof(float);
  int* sel1 = (int*)p;        p += (size_t)BB * MM * KK * sizeof(int);
  int* sel2 = (int*)p;        p += (size_t)BB * MM * KK * sizeof(int);
  float* fpre = (float*)p;    p += (size_t)BB * NN * CO * sizeof(float);
  float* y1 = (float*)p;      p += (size_t)BB * MM * CO * sizeof(float);
  float* gbuf = (float*)p;    p += (size_t)BB * MM * CO * sizeof(float);
  float* y2a = (float*)p;     p += (size_t)BB * MM * CO * sizeof(float);
  float* y2b = (float*)p;     p += (size_t)BB * MM * CO * sizeof(float);

  double* st_x = stats;          // 256
  double* mo_ps = stats + 256;   // 9 (pad 16)
  double* mo_pe = stats + 272;   // 9 (pad 16)
  double* st1 = stats + 288;     // 2*256
  double* st2a = stats + 800;    // 2*256
  double* st2b = stats + 1312;   // 2*256

#define SC(k) (scsh + (k) * 128)

  k_zero<<<8, 256, 0, stream>>>(stats);
  k_fps<<<BB, 1024, 0, stream>>>(pos, cent);
  k_conv<CI, false><<<256, 256, 0, stream>>>(x, W_x, nullptr, nullptr, fpre,
                                             st_x, (BB * NN) / 256);
  k_bq<<<(BB * MM) / 4, 256, 0, stream>>>(pos, cent, NN, 0.01f, 10.0f, sel1,
                                          mo_ps);
  k_bq<<<(BB * MM) / 4, 256, 0, stream>>>(cent, cent, MM, 0.04f, 5.0f, sel2,
                                          mo_pe);
  k_fin_stats<<<1, 128, 0, stream>>>(st_x, g_x, b_x, SC(0), SC(1),
                                     (double)(BB * NN));
  k_fin_mom<<<1, 128, 0, stream>>>(mo_ps, W_ps, g_ps, b_ps, SC(2), SC(3),
                                   (double)(BB * MM * KK));
  k_fin_mom<<<1, 128, 0, stream>>>(mo_pe, W_pe, g_pe, b_pe, SC(4), SC(5),
                                   (double)(BB * MM * KK));
  k_xf<<<BB * MM, 128, 0, stream>>>(pos, cent, sel1, fpre, W_ps, SC(2), SC(3),
                                    SC(0), SC(1), xf);
  for (int i = 0; i < 2; i++) {
    int s = 6 + i * 6;
    k_conv<CO, false><<<128, 256, 0, stream>>>(
        xf, W1 + (size_t)i * CO * CO, nullptr, nullptr, y1, st1 + i * 256,
        (BB * MM) / 128);
    k_fin_stats<<<1, 128, 0, stream>>>(st1 + i * 256, g1 + i * 128,
                                       b1 + i * 128, SC(s), SC(s + 1),
                                       (double)(BB * MM));
    k_g<<<BB * MM, 128, 0, stream>>>(cent, sel2, y1, SC(s), SC(s + 1), W_pe,
                                     SC(4), SC(5), gbuf);
    k_conv<CO, false><<<128, 256, 0, stream>>>(
        gbuf, W2a + (size_t)i * CO * CO, nullptr, nullptr, y2a, st2a + i * 256,
        (BB * MM) / 128);
    k_fin_stats<<<1, 128, 0, stream>>>(st2a + i * 256, g2a + i * 128,
                                       b2a + i * 128, SC(s + 2), SC(s + 3),
                                       (double)(BB * MM));
    k_conv<CO, true><<<128, 256, 0, stream>>>(
        y2a, W2b + (size_t)i * CO * CO, SC(s + 2), SC(s + 3), y2b,
        st2b + i * 256, (BB * MM) / 128);
    k_fin_stats<<<1, 128, 0, stream>>>(st2b + i * 256, g2b + i * 128,
                                       b2b + i * 128, SC(s + 4), SC(s + 5),
                                       (double)(BB * MM));
    k_resid<<<(BB * MM * CO) / 256, 256, 0, stream>>>(
        y1, SC(s), SC(s + 1), y2b, SC(s + 4), SC(s + 5), xf);
  }
}

// Round 2
// 4770.117 us; speedup vs baseline: 1.1237x; 1.1237x over previous
//
#include <hip/hip_runtime.h>

// StageBlocks: FPS -> ball-query -> conv/BN/max -> 2x InvResMLP on MI355X.
// All discrete decisions (FPS argmax, ball membership) use contract-off f32
// to match XLA's sub/mul/add rounding bitwise. BN handled via sufficient
// statistics (sum/sumsq per channel, or 3-dim moments for the 3->128 convs).
// R2: FPS block argmax via DPP (row_shr/row_bcast) instead of ds_swizzle
// shuffles; centroids buffered in LDS, dumped coalesced at the end.

#define BB 4
#define NN 8192
#define MM 2048
#define KK 32
#define CI 64
#define CO 128

__device__ __forceinline__ float sq3(float dx, float dy, float dz) {
#pragma clang fp contract(off)
  return dx * dx + dy * dy + dz * dz;  // ((x+y)+z), no FMA: matches XLA/np
}

// ---------------- zero stats ----------------
__global__ void k_zero(double* s) {
  int i = blockIdx.x * 256 + threadIdx.x;
  if (i < 2048) s[i] = 0.0;
}

// ---------------- DPP helpers ----------------
template <int CTRL>
__device__ __forceinline__ int dpp_i(int v) {
  return __builtin_amdgcn_update_dpp(v, v, CTRL, 0xF, 0xF, false);
}
template <int CTRL>
__device__ __forceinline__ float dpp_f(float v) {
  return __int_as_float(dpp_i<CTRL>(__float_as_int(v)));
}
// argmax combine step: (value desc, index asc) — matches argmax first-max.
template <int CTRL>
__device__ __forceinline__ void red_step(float& bv, int& bi, float& bx,
                                         float& by, float& bz) {
  float tv = dpp_f<CTRL>(bv);
  int ti = dpp_i<CTRL>(bi);
  float tx = dpp_f<CTRL>(bx);
  float ty = dpp_f<CTRL>(by);
  float tz = dpp_f<CTRL>(bz);
  bool bt = (tv > bv) || (tv == bv && ti < bi);
  bv = bt ? tv : bv;
  bi = bt ? ti : bi;
  bx = bt ? tx : bx;
  by = bt ? ty : by;
  bz = bt ? tz : bz;
}

// ---------------- FPS: one block per batch, DPP argmax ----------------
#define FT 512
#define FS (NN / FT)  // 16 points per thread, held in VGPRs

__global__ __launch_bounds__(FT) void k_fps(const float* __restrict__ pos,
                                            float* __restrict__ cent) {
  int b = blockIdx.x;
  const float* P = pos + (size_t)b * NN * 3;
  float* C = cent + (size_t)b * MM * 3;
  int t = threadIdx.x;
  int lane = t & 63, w = t >> 6;  // 8 waves
  float px[FS], py[FS], pz[FS], dis[FS];
#pragma unroll
  for (int s = 0; s < FS; s++) {
    int idx = s * FT + t;
    px[s] = P[idx * 3 + 0];
    py[s] = P[idx * 3 + 1];
    pz[s] = P[idx * 3 + 2];
    dis[s] = 1e10f;
  }
  __shared__ float4 s_l;  // current centroid broadcast
  __shared__ float s_wv[8], s_wx[8], s_wy[8], s_wz[8];
  __shared__ int s_wi[8];
  __shared__ float s_cent[MM * 3];  // 24 KB centroid staging
  if (t == 0) {
    float x0 = P[0], y0 = P[1], z0 = P[2];
    s_l = make_float4(x0, y0, z0, 0.f);
    s_cent[0] = x0;
    s_cent[1] = y0;
    s_cent[2] = z0;
  }
  __syncthreads();
  for (int m = 1; m < MM; m++) {
    float4 L = s_l;
    float lx = L.x, ly = L.y, lz = L.z;
    float bv = -1.0f, bx = 0.f, by = 0.f, bz = 0.f;
    int bi = 0;
#pragma unroll
    for (int s = 0; s < FS; s++) {
      float d2 = sq3(px[s] - lx, py[s] - ly, pz[s] - lz);
      float nd = fminf(dis[s], d2);
      dis[s] = nd;
      bool gt = nd > bv;  // strict >, ascending idx -> first-max kept
      bv = gt ? nd : bv;
      bi = gt ? s * FT + t : bi;
      bx = gt ? px[s] : bx;
      by = gt ? py[s] : by;
      bz = gt ? pz[s] : bz;
    }
    // wave64 argmax -> lane 63 (canonical GCN DPP reduction)
    red_step<0x111>(bv, bi, bx, by, bz);  // row_shr:1
    red_step<0x112>(bv, bi, bx, by, bz);  // row_shr:2
    red_step<0x114>(bv, bi, bx, by, bz);  // row_shr:4
    red_step<0x118>(bv, bi, bx, by, bz);  // row_shr:8
    red_step<0x142>(bv, bi, bx, by, bz);  // row_bcast:15
    red_step<0x143>(bv, bi, bx, by, bz);  // row_bcast:31
    if (lane == 63) {
      s_wv[w] = bv;
      s_wi[w] = bi;
      s_wx[w] = bx;
      s_wy[w] = by;
      s_wz[w] = bz;
    }
    __syncthreads();
    if (t == 0) {
      float v = s_wv[0], x = s_wx[0], y = s_wy[0], z = s_wz[0];
      int i0 = s_wi[0];
#pragma unroll
      for (int u = 1; u < 8; u++) {
        float uv = s_wv[u];
        int ui = s_wi[u];
        bool bt = (uv > v) || (uv == v && ui < i0);
        v = bt ? uv : v;
        i0 = bt ? ui : i0;
        x = bt ? s_wx[u] : x;
        y = bt ? s_wy[u] : y;
        z = bt ? s_wz[u] : z;
      }
      s_l = make_float4(x, y, z, 0.f);
      s_cent[m * 3 + 0] = x;
      s_cent[m * 3 + 1] = y;
      s_cent[m * 3 + 2] = z;
    }
    __syncthreads();
  }
  for (int i = t; i < (MM * 3) / 4; i += FT) {
    ((float4*)C)[i] = ((const float4*)s_cent)[i];
  }
}

// ---------------- ball query: one wave per (b,m) pair ----------------
// Writes first-K in-ball indices (index order, padded with first hit) and
// accumulates 9 moments of the normalized offsets (for analytic BN).
__global__ __launch_bounds__(256) void k_bq(const float* __restrict__ pts,
                                            const float* __restrict__ cent,
                                            int npts, float rsq, float inv_r,
                                            int* __restrict__ sel,
                                            double* __restrict__ mom) {
  int lane = threadIdx.x & 63, w = threadIdx.x >> 6;
  int pair = blockIdx.x * 4 + w;
  int b = pair / MM;
  const float* P = pts + (size_t)b * npts * 3;
  const float* C = cent + (size_t)pair * 3;
  float cx = C[0], cy = C[1], cz = C[2];
  __shared__ int s_sel[4][KK];
  __shared__ float s_mom[4][9];
  int cnt = 0;
  int nch = npts >> 6;
  for (int ch = 0; ch < nch; ch++) {
    int i = (ch << 6) + lane;
    float d2 = sq3(P[i * 3 + 0] - cx, P[i * 3 + 1] - cy, P[i * 3 + 2] - cz);
    bool hit = d2 < rsq;
    unsigned long long mk = __ballot(hit);
    if (mk) {
      int pre = __popcll(mk & ((1ull << lane) - 1ull));
      int k = cnt + pre;
      if (hit && k < KK) s_sel[w][k] = i;
      cnt += __popcll(mk);
      if (cnt >= KK) break;
    }
  }
  int total = cnt < KK ? cnt : KK;  // >=1 (query point is in the set, d2==0)
  int myidx = 0;
  if (lane < KK) {
    int v = (lane < total) ? s_sel[w][lane] : s_sel[w][0];
    s_sel[w][lane] = v;
    sel[(size_t)pair * KK + lane] = v;
    myidx = v;
  }
  float gx = 0.f, gy = 0.f, gz = 0.f;
  if (lane < KK) {
    gx = (P[myidx * 3 + 0] - cx) * inv_r;
    gy = (P[myidx * 3 + 1] - cy) * inv_r;
    gz = (P[myidx * 3 + 2] - cz) * inv_r;
  }
  float v9[9] = {gx, gy, gz, gx * gx, gx * gy, gx * gz, gy * gy, gy * gz, gz * gz};
#pragma unroll
  for (int j = 0; j < 9; j++) {
#pragma unroll
    for (int off = 32; off > 0; off >>= 1) v9[j] += __shfl_xor(v9[j], off);
  }
  if (lane == 0) {
#pragma unroll
    for (int j = 0; j < 9; j++) s_mom[w][j] = v9[j];
  }
  __syncthreads();
  if (threadIdx.x < 9) {
    double a = (double)s_mom[0][threadIdx.x] + s_mom[1][threadIdx.x] +
               s_mom[2][threadIdx.x] + s_mom[3][threadIdx.x];
    atomicAdd(&mom[threadIdx.x], a);
  }
}

// ---------------- pointwise conv (CIN->128) + BN stats ----------------
// thread = channel o (x2 rows); W row in VGPRs; input rows via scalar loads.
template <int CIN, bool TRANS>
__global__ __launch_bounds__(256) void k_conv(const float* __restrict__ in,
                                              const float* __restrict__ W,
                                              const float* __restrict__ isc,
                                              const float* __restrict__ ish,
                                              float* __restrict__ out,
                                              double* __restrict__ stats,
                                              int rows_per_block) {
  int o = threadIdx.x & 127, half = threadIdx.x >> 7;
  float4 w[CIN / 4];
  const float4* Wv = (const float4*)(W + (size_t)o * CIN);
#pragma unroll
  for (int i = 0; i < CIN / 4; i++) w[i] = Wv[i];
  int row0 = blockIdx.x * rows_per_block;
  float ssum = 0.f, ssq = 0.f;
  for (int r = 0; r < rows_per_block; r += 2) {
    int row = __builtin_amdgcn_readfirstlane(row0 + r + half);
    const float* xr = in + (size_t)row * CIN;
    float acc = 0.f;
#pragma unroll
    for (int i = 0; i < CIN / 4; i++) {
      float4 a = *(const float4*)(xr + 4 * i);
      if (TRANS) {
        a.x = fmaxf(a.x * isc[4 * i + 0] + ish[4 * i + 0], 0.f);
        a.y = fmaxf(a.y * isc[4 * i + 1] + ish[4 * i + 1], 0.f);
        a.z = fmaxf(a.z * isc[4 * i + 2] + ish[4 * i + 2], 0.f);
        a.w = fmaxf(a.w * isc[4 * i + 3] + ish[4 * i + 3], 0.f);
      }
      acc += a.x * w[i].x + a.y * w[i].y + a.z * w[i].z + a.w * w[i].w;
    }
    out[(size_t)row * CO + o] = acc;
    ssum += acc;
    ssq += acc * acc;
  }
  atomicAdd(&stats[o], (double)ssum);
  atomicAdd(&stats[128 + o], (double)ssq);
}

// ---------------- BN finalize: (sum,sumsq) -> scale/shift ----------------
__global__ void k_fin_stats(const double* __restrict__ st,
                            const float* __restrict__ gam,
                            const float* __restrict__ bet,
                            float* __restrict__ sc, float* __restrict__ sh,
                            double cnt) {
  int t = threadIdx.x;
  double mean = st[t] / cnt;
  double var = st[128 + t] / cnt - mean * mean;
  if (var < 0) var = 0;
  double s = (double)gam[t] / sqrt(var + 1e-5);
  sc[t] = (float)s;
  sh[t] = (float)((double)bet[t] - mean * s);
}

// BN finalize from 3-dim moments: mean_o = W mu, var_o = W S2 W^T - mean^2
__global__ void k_fin_mom(const double* __restrict__ mo,
                          const float* __restrict__ Wp,
                          const float* __restrict__ gam,
                          const float* __restrict__ bet, float* __restrict__ sc,
                          float* __restrict__ sh, double cnt) {
  int t = threadIdx.x;
  double w0 = Wp[t * 3 + 0], w1 = Wp[t * 3 + 1], w2 = Wp[t * 3 + 2];
  double mx = mo[0] / cnt, my = mo[1] / cnt, mz = mo[2] / cnt;
  double sxx = mo[3] / cnt, sxy = mo[4] / cnt, sxz = mo[5] / cnt;
  double syy = mo[6] / cnt, syz = mo[7] / cnt, szz = mo[8] / cnt;
  double mean = w0 * mx + w1 * my + w2 * mz;
  double ey2 = w0 * w0 * sxx + w1 * w1 * syy + w2 * w2 * szz +
               2.0 * (w0 * w1 * sxy + w0 * w2 * sxz + w1 * w2 * syz);
  double var = ey2 - mean * mean;
  if (var < 0) var = 0;
  double s = (double)gam[t] / sqrt(var + 1e-5);
  sc[t] = (float)s;
  sh[t] = (float)((double)bet[t] - mean * s);
}

// ---------------- stage-1 aggregation: xf = max_k(relu(bn(feat)) + relu(bn(Wps*gpn)))
__global__ __launch_bounds__(128) void k_xf(
    const float* __restrict__ pos, const float* __restrict__ cent,
    const int* __restrict__ sel1, const float* __restrict__ fpre,
    const float* __restrict__ Wps, const float* __restrict__ scp,
    const float* __restrict__ shp, const float* __restrict__ scx,
    const float* __restrict__ shx, float* __restrict__ xf) {
  int pair = blockIdx.x;
  int b = pair >> 11;
  int o = threadIdx.x;
  float w0 = Wps[o * 3 + 0], w1 = Wps[o * 3 + 1], w2 = Wps[o * 3 + 2];
  float sp = scp[o], hp = shp[o], sx = scx[o], hx = shx[o];
  const float* C = cent + (size_t)pair * 3;
  float cx = C[0], cy = C[1], cz = C[2];
  const float* P = pos + (size_t)b * NN * 3;
  const float* F = fpre + (size_t)b * NN * CO;
  __shared__ int s_idx[KK];
  if (o < KK) s_idx[o] = sel1[(size_t)pair * KK + o];
  __syncthreads();
  float acc = -1e30f;
#pragma unroll 4
  for (int k = 0; k < KK; k++) {
    int idx = __builtin_amdgcn_readfirstlane(s_idx[k]);
    float gx = (P[idx * 3 + 0] - cx) * 10.0f;
    float gy = (P[idx * 3 + 1] - cy) * 10.0f;
    float gz = (P[idx * 3 + 2] - cz) * 10.0f;
    float y = fmaxf((w0 * gx + w1 * gy + w2 * gz) * sp + hp, 0.f);
    float f = fmaxf(F[(size_t)idx * CO + o] * sx + hx, 0.f);
    float v = y + f;
    acc = v > acc ? v : acc;
  }
  xf[(size_t)pair * CO + o] = acc;
}

// ---------------- block aggregation: g = max_k(relu(bn(y1[sel2])) + pe)
__global__ __launch_bounds__(128) void k_g(
    const float* __restrict__ cent, const int* __restrict__ sel2,
    const float* __restrict__ y1, const float* __restrict__ sc1,
    const float* __restrict__ sh1, const float* __restrict__ Wpe,
    const float* __restrict__ spe, const float* __restrict__ hpe,
    float* __restrict__ g) {
  int pair = blockIdx.x;
  int b = pair >> 11;
  int o = threadIdx.x;
  float w0 = Wpe[o * 3 + 0], w1 = Wpe[o * 3 + 1], w2 = Wpe[o * 3 + 2];
  float se = spe[o], he = hpe[o], s1 = sc1[o], h1 = sh1[o];
  const float* C = cent + (size_t)pair * 3;
  float cx = C[0], cy = C[1], cz = C[2];
  const float* CB = cent + (size_t)b * MM * 3;
  const float* Y = y1 + (size_t)b * MM * CO;
  __shared__ int s_idx[KK];
  if (o < KK) s_idx[o] = sel2[(size_t)pair * KK + o];
  __syncthreads();
  float acc = -1e30f;
#pragma unroll 4
  for (int k = 0; k < KK; k++) {
    int idx = __builtin_amdgcn_readfirstlane(s_idx[k]);
    float gx = (CB[idx * 3 + 0] - cx) * 5.0f;
    float gy = (CB[idx * 3 + 1] - cy) * 5.0f;
    float gz = (CB[idx * 3 + 2] - cz) * 5.0f;
    float pe = fmaxf((w0 * gx + w1 * gy + w2 * gz) * se + he, 0.f);
    float f = fmaxf(Y[(size_t)idx * CO + o] * s1 + h1, 0.f);
    float v = pe + f;
    acc = v > acc ? v : acc;
  }
  g[(size_t)pair * CO + o] = acc;
}

// ---------------- residual: xf = relu(relu(bn(y1)) + bn(y2b)) ----------------
__global__ __launch_bounds__(256) void k_resid(
    const float* __restrict__ y1, const float* __restrict__ sc1,
    const float* __restrict__ sh1, const float* __restrict__ y2,
    const float* __restrict__ sc2, const float* __restrict__ sh2,
    float* __restrict__ xf) {
  int i = blockIdx.x * 256 + threadIdx.x;
  int o = i & 127;
  float f = fmaxf(y1[i] * sc1[o] + sh1[o], 0.f);
  float v = y2[i] * sc2[o] + sh2[o];
  xf[i] = fmaxf(f + v, 0.f);
}

extern "C" void kernel_launch(void* const* d_in, const int* in_sizes, int n_in,
                              void* d_out, int out_size, void* d_ws,
                              size_t ws_size, hipStream_t stream) {
  const float* pos = (const float*)d_in[0];
  const float* x = (const float*)d_in[1];
  const float* W_x = (const float*)d_in[2];
  const float* g_x = (const float*)d_in[3];
  const float* b_x = (const float*)d_in[4];
  const float* W_ps = (const float*)d_in[5];
  const float* g_ps = (const float*)d_in[6];
  const float* b_ps = (const float*)d_in[7];
  const float* W_pe = (const float*)d_in[8];
  const float* g_pe = (const float*)d_in[9];
  const float* b_pe = (const float*)d_in[10];
  const float* W1 = (const float*)d_in[11];
  const float* g1 = (const float*)d_in[12];
  const float* b1 = (const float*)d_in[13];
  const float* W2a = (const float*)d_in[14];
  const float* g2a = (const float*)d_in[15];
  const float* b2a = (const float*)d_in[16];
  const float* W2b = (const float*)d_in[17];
  const float* g2b = (const float*)d_in[18];
  const float* b2b = (const float*)d_in[19];

  float* cent = (float*)d_out;              // (B,M,3)
  float* xf = cent + (size_t)BB * MM * 3;   // (B,M,128)

  char* p = (char*)d_ws;
  double* stats = (double*)p; p += 2048 * sizeof(double);
  float* scsh = (float*)p;    p += 32 * 128 * sizeof(float);
  int* sel1 = (int*)p;        p += (size_t)BB * MM * KK * sizeof(int);
  int* sel2 = (int*)p;        p += (size_t)BB * MM * KK * sizeof(int);
  float* fpre = (float*)p;    p += (size_t)BB * NN * CO * sizeof(float);
  float* y1 = (float*)p;      p += (size_t)BB * MM * CO * sizeof(float);
  float* gbuf = (float*)p;    p += (size_t)BB * MM * CO * sizeof(float);
  float* y2a = (float*)p;     p += (size_t)BB * MM * CO * sizeof(float);
  float* y2b = (float*)p;     p += (size_t)BB * MM * CO * sizeof(float);

  double* st_x = stats;          // 256
  double* mo_ps = stats + 256;   // 9 (pad 16)
  double* mo_pe = stats + 272;   // 9 (pad 16)
  double* st1 = stats + 288;     // 2*256
  double* st2a = stats + 800;    // 2*256
  double* st2b = stats + 1312;   // 2*256

#define SC(k) (scsh + (k) * 128)

  k_zero<<<8, 256, 0, stream>>>(stats);
  k_fps<<<BB, FT, 0, stream>>>(pos, cent);
  k_conv<CI, false><<<256, 256, 0, stream>>>(x, W_x, nullptr, nullptr, fpre,
                                             st_x, (BB * NN) / 256);
  k_bq<<<(BB * MM) / 4, 256, 0, stream>>>(pos, cent, NN, 0.01f, 10.0f, sel1,
                                          mo_ps);
  k_bq<<<(BB * MM) / 4, 256, 0, stream>>>(cent, cent, MM, 0.04f, 5.0f, sel2,
                                          mo_pe);
  k_fin_stats<<<1, 128, 0, stream>>>(st_x, g_x, b_x, SC(0), SC(1),
                                     (double)(BB * NN));
  k_fin_mom<<<1, 128, 0, stream>>>(mo_ps, W_ps, g_ps, b_ps, SC(2), SC(3),
                                   (double)(BB * MM * KK));
  k_fin_mom<<<1, 128, 0, stream>>>(mo_pe, W_pe, g_pe, b_pe, SC(4), SC(5),
                                   (double)(BB * MM * KK));
  k_xf<<<BB * MM, 128, 0, stream>>>(pos, cent, sel1, fpre, W_ps, SC(2), SC(3),
                                    SC(0), SC(1), xf);
  for (int i = 0; i < 2; i++) {
    int s = 6 + i * 6;
    k_conv<CO, false><<<128, 256, 0, stream>>>(
        xf, W1 + (size_t)i * CO * CO, nullptr, nullptr, y1, st1 + i * 256,
        (BB * MM) / 128);
    k_fin_stats<<<1, 128, 0, stream>>>(st1 + i * 256, g1 + i * 128,
                                       b1 + i * 128, SC(s), SC(s + 1),
                                       (double)(BB * MM));
    k_g<<<BB * MM, 128, 0, stream>>>(cent, sel2, y1, SC(s), SC(s + 1), W_pe,
                                     SC(4), SC(5), gbuf);
    k_conv<CO, false><<<128, 256, 0, stream>>>(
        gbuf, W2a + (size_t)i * CO * CO, nullptr, nullptr, y2a, st2a + i * 256,
        (BB * MM) / 128);
    k_fin_stats<<<1, 128, 0, stream>>>(st2a + i * 256, g2a + i * 128,
                                       b2a + i * 128, SC(s + 2), SC(s + 3),
                                       (double)(BB * MM));
    k_conv<CO, true><<<128, 256, 0, stream>>>(
        y2a, W2b + (size_t)i * CO * CO, SC(s + 2), SC(s + 3), y2b,
        st2b + i * 256, (BB * MM) / 128);
    k_fin_stats<<<1, 128, 0, stream>>>(st2b + i * 256, g2b + i * 128,
                                       b2b + i * 128, SC(s + 4), SC(s + 5),
                                       (double)(BB * MM));
    k_resid<<<(BB * MM * CO) / 256, 256, 0, stream>>>(
        y1, SC(s), SC(s + 1), y2b, SC(s + 4), SC(s + 5), xf);
  }
}

// Round 4
// 3223.935 us; speedup vs baseline: 1.6626x; 1.4796x over previous
//
#include <hip/hip_runtime.h>

// StageBlocks: FPS -> ball-query -> conv/BN/max -> 2x InvResMLP on MI355X.
// All discrete decisions (FPS argmax, ball membership) use contract-off f32
// to match XLA/np sub/mul/add rounding bitwise. BN handled via sufficient
// statistics (sum/sumsq per channel, or 3-dim moments for the 3->128 convs).
// R3 (resubmit after infra failure): FPS argmax split into value-only max
// reduce + equality match scan + index-only min reduce; winner coords
// re-fetched via broadcast global load. Removes all payload-carrying
// cndmask chains and the serial t0 tournament.

#define BB 4
#define NN 8192
#define MM 2048
#define KK 32
#define CI 64
#define CO 128

__device__ __forceinline__ float sq3(float dx, float dy, float dz) {
#pragma clang fp contract(off)
  return dx * dx + dy * dy + dz * dz;  // ((x+y)+z), no FMA: matches XLA/np
}

// ---------------- zero stats ----------------
__global__ void k_zero(double* s) {
  int i = blockIdx.x * 256 + threadIdx.x;
  if (i < 2048) s[i] = 0.0;
}

// ---------------- DPP helpers ----------------
template <int CTRL>
__device__ __forceinline__ int dpp_i(int v) {
  return __builtin_amdgcn_update_dpp(v, v, CTRL, 0xF, 0xF, false);
}
template <int CTRL>
__device__ __forceinline__ float dpp_f(float v) {
  return __int_as_float(dpp_i<CTRL>(__float_as_int(v)));
}

// ---------------- FPS: one block per batch ----------------
// Two-phase block argmax: (1) value-only max via DPP + LDS fold,
// (2) equality match -> index-only min via DPP + LDS fold.
#define FT 512
#define FS (NN / FT)  // 16 points per thread, held in VGPRs
#define NW (FT / 64)  // 8 waves

__global__ __launch_bounds__(FT) void k_fps(const float* __restrict__ pos,
                                            float* __restrict__ cent) {
  int b = blockIdx.x;
  const float* P = pos + (size_t)b * NN * 3;
  float* C = cent + (size_t)b * MM * 3;
  int t = threadIdx.x;
  int lane = t & 63, w = t >> 6;
  float px[FS], py[FS], pz[FS], dis[FS];
#pragma unroll
  for (int s = 0; s < FS; s++) {
    int idx = s * FT + t;
    px[s] = P[idx * 3 + 0];
    py[s] = P[idx * 3 + 1];
    pz[s] = P[idx * 3 + 2];
    dis[s] = 1e10f;
  }
  __shared__ alignas(16) float s_wv[NW];
  __shared__ alignas(16) int s_wi[NW];
  __shared__ float s_cent[MM * 3];  // 24 KB centroid staging
  float lx = P[0], ly = P[1], lz = P[2];
  if (t == 0) {
    s_cent[0] = lx;
    s_cent[1] = ly;
    s_cent[2] = lz;
  }
  for (int m = 1; m < MM; m++) {
    // phase 1: global max of updated min-distances
    float bv = -1.0f;
#pragma unroll
    for (int s = 0; s < FS; s++) {
      float d2 = sq3(px[s] - lx, py[s] - ly, pz[s] - lz);
      float nd = fminf(dis[s], d2);
      dis[s] = nd;
      bv = fmaxf(bv, nd);
    }
    bv = fmaxf(bv, dpp_f<0x111>(bv));  // row_shr:1
    bv = fmaxf(bv, dpp_f<0x112>(bv));  // row_shr:2
    bv = fmaxf(bv, dpp_f<0x114>(bv));  // row_shr:4
    bv = fmaxf(bv, dpp_f<0x118>(bv));  // row_shr:8
    bv = fmaxf(bv, dpp_f<0x142>(bv));  // row_bcast:15
    bv = fmaxf(bv, dpp_f<0x143>(bv));  // row_bcast:31
    if (lane == 63) s_wv[w] = bv;
    __syncthreads();
    float4 va = ((const float4*)s_wv)[0];
    float4 vb = ((const float4*)s_wv)[1];
    float gmax = fmaxf(fmaxf(fmaxf(va.x, va.y), fmaxf(va.z, va.w)),
                       fmaxf(fmaxf(vb.x, vb.y), fmaxf(vb.z, vb.w)));
    // phase 2: smallest index attaining gmax (numpy argmax tie-break)
    int bi = 0x7fffffff;
#pragma unroll
    for (int s = 0; s < FS; s++) {
      int idx = s * FT + t;
      bi = (dis[s] == gmax) ? (idx < bi ? idx : bi) : bi;
    }
    {
      int u;
      u = dpp_i<0x111>(bi); bi = u < bi ? u : bi;
      u = dpp_i<0x112>(bi); bi = u < bi ? u : bi;
      u = dpp_i<0x114>(bi); bi = u < bi ? u : bi;
      u = dpp_i<0x118>(bi); bi = u < bi ? u : bi;
      u = dpp_i<0x142>(bi); bi = u < bi ? u : bi;
      u = dpp_i<0x143>(bi); bi = u < bi ? u : bi;
    }
    if (lane == 63) s_wi[w] = bi;
    __syncthreads();
    int4 ia = ((const int4*)s_wi)[0];
    int4 ib = ((const int4*)s_wi)[1];
    int g0 = ia.x < ia.y ? ia.x : ia.y;
    int g1 = ia.z < ia.w ? ia.z : ia.w;
    int g2 = ib.x < ib.y ? ib.x : ib.y;
    int g3 = ib.z < ib.w ? ib.z : ib.w;
    g0 = g0 < g1 ? g0 : g1;
    g2 = g2 < g3 ? g2 : g3;
    int gidx = g0 < g2 ? g0 : g2;
    // broadcast winner coords: same-address global load (L2-hot)
    lx = P[gidx * 3 + 0];
    ly = P[gidx * 3 + 1];
    lz = P[gidx * 3 + 2];
    if (t == 0) {
      s_cent[m * 3 + 0] = lx;
      s_cent[m * 3 + 1] = ly;
      s_cent[m * 3 + 2] = lz;
    }
  }
  __syncthreads();
  for (int i = t; i < (MM * 3) / 4; i += FT) {
    ((float4*)C)[i] = ((const float4*)s_cent)[i];
  }
}

// ---------------- ball query: one wave per (b,m) pair ----------------
// Writes first-K in-ball indices (index order, padded with first hit) and
// accumulates 9 moments of the normalized offsets (for analytic BN).
__global__ __launch_bounds__(256) void k_bq(const float* __restrict__ pts,
                                            const float* __restrict__ cent,
                                            int npts, float rsq, float inv_r,
                                            int* __restrict__ sel,
                                            double* __restrict__ mom) {
  int lane = threadIdx.x & 63, w = threadIdx.x >> 6;
  int pair = blockIdx.x * 4 + w;
  int b = pair / MM;
  const float* P = pts + (size_t)b * npts * 3;
  const float* C = cent + (size_t)pair * 3;
  float cx = C[0], cy = C[1], cz = C[2];
  __shared__ int s_sel[4][KK];
  __shared__ float s_mom[4][9];
  int cnt = 0;
  int nch = npts >> 6;
  for (int ch = 0; ch < nch; ch++) {
    int i = (ch << 6) + lane;
    float d2 = sq3(P[i * 3 + 0] - cx, P[i * 3 + 1] - cy, P[i * 3 + 2] - cz);
    bool hit = d2 < rsq;
    unsigned long long mk = __ballot(hit);
    if (mk) {
      int pre = __popcll(mk & ((1ull << lane) - 1ull));
      int k = cnt + pre;
      if (hit && k < KK) s_sel[w][k] = i;
      cnt += __popcll(mk);
      if (cnt >= KK) break;
    }
  }
  int total = cnt < KK ? cnt : KK;  // >=1 (query point is in the set, d2==0)
  int myidx = 0;
  if (lane < KK) {
    int v = (lane < total) ? s_sel[w][lane] : s_sel[w][0];
    s_sel[w][lane] = v;
    sel[(size_t)pair * KK + lane] = v;
    myidx = v;
  }
  float gx = 0.f, gy = 0.f, gz = 0.f;
  if (lane < KK) {
    gx = (P[myidx * 3 + 0] - cx) * inv_r;
    gy = (P[myidx * 3 + 1] - cy) * inv_r;
    gz = (P[myidx * 3 + 2] - cz) * inv_r;
  }
  float v9[9] = {gx, gy, gz, gx * gx, gx * gy, gx * gz, gy * gy, gy * gz, gz * gz};
#pragma unroll
  for (int j = 0; j < 9; j++) {
#pragma unroll
    for (int off = 32; off > 0; off >>= 1) v9[j] += __shfl_xor(v9[j], off);
  }
  if (lane == 0) {
#pragma unroll
    for (int j = 0; j < 9; j++) s_mom[w][j] = v9[j];
  }
  __syncthreads();
  if (threadIdx.x < 9) {
    double a = (double)s_mom[0][threadIdx.x] + s_mom[1][threadIdx.x] +
               s_mom[2][threadIdx.x] + s_mom[3][threadIdx.x];
    atomicAdd(&mom[threadIdx.x], a);
  }
}

// ---------------- pointwise conv (CIN->128) + BN stats ----------------
// thread = channel o (x2 rows); W row in VGPRs; input rows via scalar loads.
template <int CIN, bool TRANS>
__global__ __launch_bounds__(256) void k_conv(const float* __restrict__ in,
                                              const float* __restrict__ W,
                                              const float* __restrict__ isc,
                                              const float* __restrict__ ish,
                                              float* __restrict__ out,
                                              double* __restrict__ stats,
                                              int rows_per_block) {
  int o = threadIdx.x & 127, half = threadIdx.x >> 7;
  float4 w[CIN / 4];
  const float4* Wv = (const float4*)(W + (size_t)o * CIN);
#pragma unroll
  for (int i = 0; i < CIN / 4; i++) w[i] = Wv[i];
  int row0 = blockIdx.x * rows_per_block;
  float ssum = 0.f, ssq = 0.f;
  for (int r = 0; r < rows_per_block; r += 2) {
    int row = __builtin_amdgcn_readfirstlane(row0 + r + half);
    const float* xr = in + (size_t)row * CIN;
    float acc = 0.f;
#pragma unroll
    for (int i = 0; i < CIN / 4; i++) {
      float4 a = *(const float4*)(xr + 4 * i);
      if (TRANS) {
        a.x = fmaxf(a.x * isc[4 * i + 0] + ish[4 * i + 0], 0.f);
        a.y = fmaxf(a.y * isc[4 * i + 1] + ish[4 * i + 1], 0.f);
        a.z = fmaxf(a.z * isc[4 * i + 2] + ish[4 * i + 2], 0.f);
        a.w = fmaxf(a.w * isc[4 * i + 3] + ish[4 * i + 3], 0.f);
      }
      acc += a.x * w[i].x + a.y * w[i].y + a.z * w[i].z + a.w * w[i].w;
    }
    out[(size_t)row * CO + o] = acc;
    ssum += acc;
    ssq += acc * acc;
  }
  atomicAdd(&stats[o], (double)ssum);
  atomicAdd(&stats[128 + o], (double)ssq);
}

// ---------------- BN finalize: (sum,sumsq) -> scale/shift ----------------
__global__ void k_fin_stats(const double* __restrict__ st,
                            const float* __restrict__ gam,
                            const float* __restrict__ bet,
                            float* __restrict__ sc, float* __restrict__ sh,
                            double cnt) {
  int t = threadIdx.x;
  double mean = st[t] / cnt;
  double var = st[128 + t] / cnt - mean * mean;
  if (var < 0) var = 0;
  double s = (double)gam[t] / sqrt(var + 1e-5);
  sc[t] = (float)s;
  sh[t] = (float)((double)bet[t] - mean * s);
}

// BN finalize from 3-dim moments: mean_o = W mu, var_o = W S2 W^T - mean^2
__global__ void k_fin_mom(const double* __restrict__ mo,
                          const float* __restrict__ Wp,
                          const float* __restrict__ gam,
                          const float* __restrict__ bet, float* __restrict__ sc,
                          float* __restrict__ sh, double cnt) {
  int t = threadIdx.x;
  double w0 = Wp[t * 3 + 0], w1 = Wp[t * 3 + 1], w2 = Wp[t * 3 + 2];
  double mx = mo[0] / cnt, my = mo[1] / cnt, mz = mo[2] / cnt;
  double sxx = mo[3] / cnt, sxy = mo[4] / cnt, sxz = mo[5] / cnt;
  double syy = mo[6] / cnt, syz = mo[7] / cnt, szz = mo[8] / cnt;
  double mean = w0 * mx + w1 * my + w2 * mz;
  double ey2 = w0 * w0 * sxx + w1 * w1 * syy + w2 * w2 * szz +
               2.0 * (w0 * w1 * sxy + w0 * w2 * sxz + w1 * w2 * syz);
  double var = ey2 - mean * mean;
  if (var < 0) var = 0;
  double s = (double)gam[t] / sqrt(var + 1e-5);
  sc[t] = (float)s;
  sh[t] = (float)((double)bet[t] - mean * s);
}

// ---------------- stage-1 aggregation: xf = max_k(relu(bn(feat)) + relu(bn(Wps*gpn)))
__global__ __launch_bounds__(128) void k_xf(
    const float* __restrict__ pos, const float* __restrict__ cent,
    const int* __restrict__ sel1, const float* __restrict__ fpre,
    const float* __restrict__ Wps, const float* __restrict__ scp,
    const float* __restrict__ shp, const float* __restrict__ scx,
    const float* __restrict__ shx, float* __restrict__ xf) {
  int pair = blockIdx.x;
  int b = pair >> 11;
  int o = threadIdx.x;
  float w0 = Wps[o * 3 + 0], w1 = Wps[o * 3 + 1], w2 = Wps[o * 3 + 2];
  float sp = scp[o], hp = shp[o], sx = scx[o], hx = shx[o];
  const float* C = cent + (size_t)pair * 3;
  float cx = C[0], cy = C[1], cz = C[2];
  const float* P = pos + (size_t)b * NN * 3;
  const float* F = fpre + (size_t)b * NN * CO;
  __shared__ int s_idx[KK];
  if (o < KK) s_idx[o] = sel1[(size_t)pair * KK + o];
  __syncthreads();
  float acc = -1e30f;
#pragma unroll 4
  for (int k = 0; k < KK; k++) {
    int idx = __builtin_amdgcn_readfirstlane(s_idx[k]);
    float gx = (P[idx * 3 + 0] - cx) * 10.0f;
    float gy = (P[idx * 3 + 1] - cy) * 10.0f;
    float gz = (P[idx * 3 + 2] - cz) * 10.0f;
    float y = fmaxf((w0 * gx + w1 * gy + w2 * gz) * sp + hp, 0.f);
    float f = fmaxf(F[(size_t)idx * CO + o] * sx + hx, 0.f);
    float v = y + f;
    acc = v > acc ? v : acc;
  }
  xf[(size_t)pair * CO + o] = acc;
}

// ---------------- block aggregation: g = max_k(relu(bn(y1[sel2])) + pe)
__global__ __launch_bounds__(128) void k_g(
    const float* __restrict__ cent, const int* __restrict__ sel2,
    const float* __restrict__ y1, const float* __restrict__ sc1,
    const float* __restrict__ sh1, const float* __restrict__ Wpe,
    const float* __restrict__ spe, const float* __restrict__ hpe,
    float* __restrict__ g) {
  int pair = blockIdx.x;
  int b = pair >> 11;
  int o = threadIdx.x;
  float w0 = Wpe[o * 3 + 0], w1 = Wpe[o * 3 + 1], w2 = Wpe[o * 3 + 2];
  float se = spe[o], he = hpe[o], s1 = sc1[o], h1 = sh1[o];
  const float* C = cent + (size_t)pair * 3;
  float cx = C[0], cy = C[1], cz = C[2];
  const float* CB = cent + (size_t)b * MM * 3;
  const float* Y = y1 + (size_t)b * MM * CO;
  __shared__ int s_idx[KK];
  if (o < KK) s_idx[o] = sel2[(size_t)pair * KK + o];
  __syncthreads();
  float acc = -1e30f;
#pragma unroll 4
  for (int k = 0; k < KK; k++) {
    int idx = __builtin_amdgcn_readfirstlane(s_idx[k]);
    float gx = (CB[idx * 3 + 0] - cx) * 5.0f;
    float gy = (CB[idx * 3 + 1] - cy) * 5.0f;
    float gz = (CB[idx * 3 + 2] - cz) * 5.0f;
    float pe = fmaxf((w0 * gx + w1 * gy + w2 * gz) * se + he, 0.f);
    float f = fmaxf(Y[(size_t)idx * CO + o] * s1 + h1, 0.f);
    float v = pe + f;
    acc = v > acc ? v : acc;
  }
  g[(size_t)pair * CO + o] = acc;
}

// ---------------- residual: xf = relu(relu(bn(y1)) + bn(y2b)) ----------------
__global__ __launch_bounds__(256) void k_resid(
    const float* __restrict__ y1, const float* __restrict__ sc1,
    const float* __restrict__ sh1, const float* __restrict__ y2,
    const float* __restrict__ sc2, const float* __restrict__ sh2,
    float* __restrict__ xf) {
  int i = blockIdx.x * 256 + threadIdx.x;
  int o = i & 127;
  float f = fmaxf(y1[i] * sc1[o] + sh1[o], 0.f);
  float v = y2[i] * sc2[o] + sh2[o];
  xf[i] = fmaxf(f + v, 0.f);
}

extern "C" void kernel_launch(void* const* d_in, const int* in_sizes, int n_in,
                              void* d_out, int out_size, void* d_ws,
                              size_t ws_size, hipStream_t stream) {
  const float* pos = (const float*)d_in[0];
  const float* x = (const float*)d_in[1];
  const float* W_x = (const float*)d_in[2];
  const float* g_x = (const float*)d_in[3];
  const float* b_x = (const float*)d_in[4];
  const float* W_ps = (const float*)d_in[5];
  const float* g_ps = (const float*)d_in[6];
  const float* b_ps = (const float*)d_in[7];
  const float* W_pe = (const float*)d_in[8];
  const float* g_pe = (const float*)d_in[9];
  const float* b_pe = (const float*)d_in[10];
  const float* W1 = (const float*)d_in[11];
  const float* g1 = (const float*)d_in[12];
  const float* b1 = (const float*)d_in[13];
  const float* W2a = (const float*)d_in[14];
  const float* g2a = (const float*)d_in[15];
  const float* b2a = (const float*)d_in[16];
  const float* W2b = (const float*)d_in[17];
  const float* g2b = (const float*)d_in[18];
  const float* b2b = (const float*)d_in[19];

  float* cent = (float*)d_out;              // (B,M,3)
  float* xf = cent + (size_t)BB * MM * 3;   // (B,M,128)

  char* p = (char*)d_ws;
  double* stats = (double*)p; p += 2048 * sizeof(double);
  float* scsh = (float*)p;    p += 32 * 128 * sizeof(float);
  int* sel1 = (int*)p;        p += (size_t)BB * MM * KK * sizeof(int);
  int* sel2 = (int*)p;        p += (size_t)BB * MM * KK * sizeof(int);
  float* fpre = (float*)p;    p += (size_t)BB * NN * CO * sizeof(float);
  float* y1 = (float*)p;      p += (size_t)BB * MM * CO * sizeof(float);
  float* gbuf = (float*)p;    p += (size_t)BB * MM * CO * sizeof(float);
  float* y2a = (float*)p;     p += (size_t)BB * MM * CO * sizeof(float);
  float* y2b = (float*)p;     p += (size_t)BB * MM * CO * sizeof(float);

  double* st_x = stats;          // 256
  double* mo_ps = stats + 256;   // 9 (pad 16)
  double* mo_pe = stats + 272;   // 9 (pad 16)
  double* st1 = stats + 288;     // 2*256
  double* st2a = stats + 800;    // 2*256
  double* st2b = stats + 1312;   // 2*256

#define SC(k) (scsh + (k) * 128)

  k_zero<<<8, 256, 0, stream>>>(stats);
  k_fps<<<BB, FT, 0, stream>>>(pos, cent);
  k_conv<CI, false><<<256, 256, 0, stream>>>(x, W_x, nullptr, nullptr, fpre,
                                             st_x, (BB * NN) / 256);
  k_bq<<<(BB * MM) / 4, 256, 0, stream>>>(pos, cent, NN, 0.01f, 10.0f, sel1,
                                          mo_ps);
  k_bq<<<(BB * MM) / 4, 256, 0, stream>>>(cent, cent, MM, 0.04f, 5.0f, sel2,
                                          mo_pe);
  k_fin_stats<<<1, 128, 0, stream>>>(st_x, g_x, b_x, SC(0), SC(1),
                                     (double)(BB * NN));
  k_fin_mom<<<1, 128, 0, stream>>>(mo_ps, W_ps, g_ps, b_ps, SC(2), SC(3),
                                   (double)(BB * MM * KK));
  k_fin_mom<<<1, 128, 0, stream>>>(mo_pe, W_pe, g_pe, b_pe, SC(4), SC(5),
                                   (double)(BB * MM * KK));
  k_xf<<<BB * MM, 128, 0, stream>>>(pos, cent, sel1, fpre, W_ps, SC(2), SC(3),
                                    SC(0), SC(1), xf);
  for (int i = 0; i < 2; i++) {
    int s = 6 + i * 6;
    k_conv<CO, false><<<128, 256, 0, stream>>>(
        xf, W1 + (size_t)i * CO * CO, nullptr, nullptr, y1, st1 + i * 256,
        (BB * MM) / 128);
    k_fin_stats<<<1, 128, 0, stream>>>(st1 + i * 256, g1 + i * 128,
                                       b1 + i * 128, SC(s), SC(s + 1),
                                       (double)(BB * MM));
    k_g<<<BB * MM, 128, 0, stream>>>(cent, sel2, y1, SC(s), SC(s + 1), W_pe,
                                     SC(4), SC(5), gbuf);
    k_conv<CO, false><<<128, 256, 0, stream>>>(
        gbuf, W2a + (size_t)i * CO * CO, nullptr, nullptr, y2a, st2a + i * 256,
        (BB * MM) / 128);
    k_fin_stats<<<1, 128, 0, stream>>>(st2a + i * 256, g2a + i * 128,
                                       b2a + i * 128, SC(s + 2), SC(s + 3),
                                       (double)(BB * MM));
    k_conv<CO, true><<<128, 256, 0, stream>>>(
        y2a, W2b + (size_t)i * CO * CO, SC(s + 2), SC(s + 3), y2b,
        st2b + i * 256, (BB * MM) / 128);
    k_fin_stats<<<1, 128, 0, stream>>>(st2b + i * 256, g2b + i * 128,
                                       b2b + i * 128, SC(s + 4), SC(s + 5),
                                       (double)(BB * MM));
    k_resid<<<(BB * MM * CO) / 256, 256, 0, stream>>>(
        y1, SC(s), SC(s + 1), y2b, SC(s + 4), SC(s + 5), xf);
  }
}